// Round 10
// baseline (206.271 us; speedup 1.0000x reference)
//
#include <hip/hip_runtime.h>
#include <stdint.h>
#include <math.h>

typedef unsigned short u16;
typedef unsigned int u32;
typedef __bf16 bf16x8 __attribute__((ext_vector_type(8)));
typedef unsigned short u16x8 __attribute__((ext_vector_type(8)));
typedef unsigned short u16x4 __attribute__((ext_vector_type(4)));
typedef float f32x4 __attribute__((ext_vector_type(4)));
typedef float f32x16 __attribute__((ext_vector_type(16)));

#define MFMA16(a, b, c) __builtin_amdgcn_mfma_f32_16x16x32_bf16((a), (b), (c), 0, 0, 0)
#define MFMA32(a, b, c) __builtin_amdgcn_mfma_f32_32x32x16_bf16((a), (b), (c), 0, 0, 0)

__device__ __forceinline__ u16 f2b(float f) {
    union { unsigned int i; float f; } v; v.f = f;
    unsigned int r = (v.i + 0x7FFFu + ((v.i >> 16) & 1u)) >> 16;
    return (u16)r;
}
// packed f32x2 -> bf16x2 (RNE), 1 VALU instruction (T12 recipe)
__device__ __forceinline__ u32 cvtpk(float lo, float hi) {
    u32 r; asm("v_cvt_pk_bf16_f32 %0, %1, %2" : "=v"(r) : "v"(lo), "v"(hi));
    return r;
}
// async global->LDS, 16B per lane. HW dest = wave-uniform base + lane*16.
__device__ __forceinline__ void gload16(const void* g, void* l) {
    __builtin_amdgcn_global_load_lds(
        (const __attribute__((address_space(1))) u32*)g,
        (__attribute__((address_space(3))) u32*)l, 16, 0, 0);
}

constexpr int N = 4096;
constexpr int Cc = 128;
constexpr int Fc = 128;
constexpr int BATCH = 4;
constexpr int NT = N / 128;     // 32 key tiles of 128 keys
constexpr int NBLK = 256;       // grid size == CU count (co-resident)

constexpr int WL_S  = 132;  // W staging  [c][f]
constexpr int WT_S  = 136;  // W transposed [f][c]
constexpr int X_S   = 136;  // X tiles [m][c]
constexpr int KO_S  = 136;  // K repack [row][f]
constexpr int VO_S  = 72;   // V repack [ch][key]
constexpr int QLS_S = 132;  // Q tile (persists across grid barrier)
constexpr int OM_STRIDE = 130;

// Q projection scale: (1/sqrt(128)) * log2(e)  -> softmax runs in exp2 domain
#define QSCALE 0.12751744750f

// LDS map (bytes):
//  phase 1 (proj): Wl 0..33792 | Wt 33792..68608 | Xq 68608..86016 |
//                  Xkv 86016..103424 | Ko alias Xq | Vo alias Wl
//  phase 2 (attn): B0 0..65536 | B1 65536..131072 | merge Om/Lm alias 0..134144
//  both: Qls 131072..147968 (dead after aq read; merge may overwrite)
__global__ __launch_bounds__(512, 2) void fused_kernel(
    const float* __restrict__ q_in, const float* __restrict__ kv_in,
    const float* __restrict__ Wq, const float* __restrict__ bq,
    const float* __restrict__ Wk, const float* __restrict__ bk,
    const float* __restrict__ Wv, const float* __restrict__ bv,
    u16* __restrict__ Kw, u16* __restrict__ Vtw,
    int* __restrict__ bar, float* __restrict__ out)
{
    __shared__ __align__(16) char smem[147968];
    u16* const Wl  = (u16*)(smem);
    u16* const Wt  = (u16*)(smem + 33792);
    u16* const Xq  = (u16*)(smem + 68608);
    u16* const Xkv = (u16*)(smem + 86016);
    u16* const Ko  = (u16*)(smem + 68608);   // alias Xq (dead when used)
    u16* const Vo  = (u16*)(smem);           // alias Wl (dead when used)
    u16* const Qls = (u16*)(smem + 131072);

    const int tid = threadIdx.x;
    // XCD-aware remap: blocks with equal (id&7) share a batch. Same (b, m0)
    // serves proj (rows written) and attn (q-rows consumed) -> Q stays in LDS.
    const int id = blockIdx.x + 64 * blockIdx.y;
    const int b = (id >> 1) & 3;
    const int m0 = (((id & 1) << 5) + (id >> 3)) << 6;

    const int lane = tid & 63;
    const int w = tid >> 6;      // 0..7
    const int n16 = lane & 15;
    const int quad = lane >> 4;

    // =================== PHASE 1: projections (this block's 64 rows) ======
    {
        const float* Xg = q_in  + ((size_t)b * N + m0) * Cc;
        const float* Xk = kv_in + ((size_t)b * N + m0) * Cc;
#pragma unroll
        for (int it = 0; it < 4; ++it) {
            int idx4 = tid + it * 512; int e0 = idx4 * 4;
            int r = e0 >> 7, c = e0 & 127;
            float4 xv = *(const float4*)(Xg + e0);
            u16x4 h; h[0] = f2b(xv.x); h[1] = f2b(xv.y); h[2] = f2b(xv.z); h[3] = f2b(xv.w);
            *(u16x4*)&Xq[r * X_S + c] = h;
            float4 kv = *(const float4*)(Xk + e0);
            u16x4 g; g[0] = f2b(kv.x); g[1] = f2b(kv.y); g[2] = f2b(kv.z); g[3] = f2b(kv.w);
            *(u16x4*)&Xkv[r * X_S + c] = g;
        }
    }

    auto STAGE_W = [&](const float* W) {
#pragma unroll
        for (int it = 0; it < 8; ++it) {
            int idx4 = tid + it * 512; int e0 = idx4 * 4;
            int c = e0 >> 7, f = e0 & 127;
            float4 wv = *(const float4*)(W + e0);
            u16x4 h; h[0] = f2b(wv.x); h[1] = f2b(wv.y); h[2] = f2b(wv.z); h[3] = f2b(wv.w);
            *(u16x4*)&Wl[c * WL_S + f] = h;
        }
    };
    auto TRANS_W = [&]() {
#pragma unroll
        for (int it = 0; it < 4; ++it) {
            int idx8 = tid + it * 512; int e0 = idx8 * 8;
            int f = e0 >> 7, c = e0 & 127;
            u16x8 h;
#pragma unroll
            for (int j = 0; j < 8; ++j) h[j] = Wl[(c + j) * WL_S + f];
            *(u16x8*)&Wt[f * WT_S + c] = h;
        }
    };

    const int msub = w & 3;          // m-subtile (16 rows) for Q/K paths
    const int ftb  = (w >> 2) * 4;   // ft range start for Q/K paths

    // ---- Q -> Qls (never leaves the block)
    STAGE_W(Wq);
    __syncthreads();
    TRANS_W();
    __syncthreads();
    {
        bf16x8 ax[4];
#pragma unroll
        for (int kk = 0; kk < 4; ++kk)
            ax[kk] = *(const bf16x8*)&Xq[(msub * 16 + n16) * X_S + kk * 32 + quad * 8];
#pragma unroll
        for (int f2 = 0; f2 < 4; ++f2) {
            int ft = ftb + f2;
            f32x4 acc = {0.f, 0.f, 0.f, 0.f};
#pragma unroll
            for (int kk = 0; kk < 4; ++kk) {
                bf16x8 bw = *(const bf16x8*)&Wt[(ft * 16 + n16) * WT_S + kk * 32 + quad * 8];
                acc = MFMA16(ax[kk], bw, acc);
            }
            float bias_f = bq[ft * 16 + n16];
#pragma unroll
            for (int r = 0; r < 4; ++r) {
                int rl = msub * 16 + quad * 4 + r;
                Qls[rl * QLS_S + ft * 16 + n16] = f2b((acc[r] + bias_f) * QSCALE);
            }
        }
    }
    __syncthreads();

    // ---- K -> frag-major global (r9-verified map, coalesced emit)
    STAGE_W(Wk);
    __syncthreads();
    TRANS_W();
    __syncthreads();
    {
        bf16x8 ax[4];
#pragma unroll
        for (int kk = 0; kk < 4; ++kk)
            ax[kk] = *(const bf16x8*)&Xkv[(msub * 16 + n16) * X_S + kk * 32 + quad * 8];
        float accs[4][4]; float biasf[4];
#pragma unroll
        for (int f2 = 0; f2 < 4; ++f2) {
            int ft = ftb + f2;
            f32x4 acc = {0.f, 0.f, 0.f, 0.f};
#pragma unroll
            for (int kk = 0; kk < 4; ++kk) {
                bf16x8 bw = *(const bf16x8*)&Wt[(ft * 16 + n16) * WT_S + kk * 32 + quad * 8];
                acc = MFMA16(ax[kk], bw, acc);
            }
            biasf[f2] = bk[ft * 16 + n16];
#pragma unroll
            for (int r = 0; r < 4; ++r) accs[f2][r] = acc[r];
        }
        // Ko aliases Xq (dead) — safe to write without an extra barrier
#pragma unroll
        for (int f2 = 0; f2 < 4; ++f2)
#pragma unroll
            for (int r = 0; r < 4; ++r) {
                int rl = msub * 16 + quad * 4 + r;
                int f = (ftb + f2) * 16 + n16;
                Ko[rl * KO_S + f] = f2b(accs[f2][r] + biasf[f2]);
            }
    }
    __syncthreads();
    {
        u16* const outK = Kw + ((size_t)b * 1024 + (m0 >> 5) * 8) * 512;
#pragma unroll
        for (int it = 0; it < 2; ++it) {
            int e = tid * 8 + it * 4096;
            int lg = e >> 12, rem = e & 4095;
            int kk2 = rem >> 9, rem2 = rem & 511;
            int hig = rem2 >> 8, l31v = (rem2 >> 3) & 31;
            int rl = lg * 32 + l31v;
            int fb = kk2 * 16 + hig * 8;
            *(u16x8*)(outK + e) = *(const u16x8*)&Ko[rl * KO_S + fb];
        }
    }
    __syncthreads();

    // ---- V -> frag-major global
    STAGE_W(Wv);
    __syncthreads();
    TRANS_W();
    __syncthreads();
    {
        const int ftg = w;   // 8 waves x 16 channels
        bf16x8 aw[4];
#pragma unroll
        for (int kk = 0; kk < 4; ++kk)
            aw[kk] = *(const bf16x8*)&Wt[(ftg * 16 + n16) * WT_S + kk * 32 + quad * 8];
        float bias4[4];
#pragma unroll
        for (int r = 0; r < 4; ++r) bias4[r] = bv[ftg * 16 + quad * 4 + r];
        float accs[4][4];
#pragma unroll
        for (int nt = 0; nt < 4; ++nt) {
            f32x4 acc = {0.f, 0.f, 0.f, 0.f};
#pragma unroll
            for (int kk = 0; kk < 4; ++kk) {
                bf16x8 bx = *(const bf16x8*)&Xkv[(nt * 16 + n16) * X_S + kk * 32 + quad * 8];
                acc = MFMA16(aw[kk], bx, acc);
            }
#pragma unroll
            for (int r = 0; r < 4; ++r) accs[nt][r] = acc[r];
        }
        // Vo aliases Wl (dead after transpose)
#pragma unroll
        for (int nt = 0; nt < 4; ++nt)
#pragma unroll
            for (int r = 0; r < 4; ++r) {
                int fg = ftg * 16 + quad * 4 + r;
                int kl = nt * 16 + n16;
                Vo[fg * VO_S + kl] = f2b(accs[nt][r] + bias4[r]);
            }
    }
    __syncthreads();
    {
        u16* const outV = Vtw + ((size_t)b * 1024 + (m0 >> 5) * 8) * 512;
#pragma unroll
        for (int it = 0; it < 2; ++it) {
            int e = tid * 8 + it * 4096;
            int lg = e >> 12, rem = e & 4095;
            int grp = rem >> 9, rem2 = rem & 511;
            int cb = grp >> 1, ks = grp & 1;
            int hig = rem2 >> 8, l31v = (rem2 >> 3) & 31;
            int ch = cb * 32 + l31v;
            int kb = lg * 32 + ks * 16 + hig * 8;
            *(u16x8*)(outV + e) = *(const u16x8*)&Vo[ch * VO_S + kb];
        }
    }

    // =================== GRID BARRIER (all 256 blocks co-resident) ========
    __syncthreads();
    __threadfence();                         // release: agent-scope L2 writeback
    if (tid == 0) {
        atomicAdd(bar, 1);
        int v = atomicAdd(bar, 0);
        int guard = 0;
        while (v < NBLK && guard < (1 << 18)) {
            __builtin_amdgcn_s_sleep(8);     // backoff: ~512 cy between polls
            v = atomicAdd(bar, 0);
            ++guard;
        }
    }
    __syncthreads();
    __threadfence();                         // acquire: invalidate stale caches

    // =================== PHASE 2: flash attention (r9 kernel) =============
    u16* const B0 = (u16*)smem;
    u16* const B1 = (u16*)(smem + 65536);

    const int kg = w & 3;
    const int qg = w >> 2;
    const int l31 = lane & 31;
    const int hi = lane >> 5;
    const int q0 = m0;

    bf16x8 aq[8];
#pragma unroll
    for (int kk = 0; kk < 8; ++kk)
        aq[kk] = *(const bf16x8*)&Qls[(qg * 32 + l31) * QLS_S + hi * 8 + kk * 16];

    const u16* const Ktile = Kw + (size_t)b * 1024 * 512;
    const u16* const Vtile = Vtw + (size_t)b * 1024 * 512;
    const int kro = kg * 4096 + lane * 8;
    const int vro = kg * 4096 + lane * 8;

    f32x16 o[4];
#pragma unroll
    for (int cb = 0; cb < 4; ++cb)
#pragma unroll
        for (int i = 0; i < 16; ++i) o[cb][i] = 0.f;
    float lloc = 0.f;

    int ci[4];
#pragma unroll
    for (int it = 0; it < 4; ++it) ci[it] = tid + it * 512;

    auto STAGE = [&](u16* bd, int t) {
        const u16* ksrc = Ktile + (size_t)t * 16384;
        const u16* vsrc = Vtile + (size_t)t * 16384;
#pragma unroll
        for (int it = 0; it < 4; ++it)
            gload16(ksrc + ci[it] * 8, bd + ci[it] * 8);
#pragma unroll
        for (int it = 0; it < 4; ++it)
            gload16(vsrc + ci[it] * 8, bd + 16384 + ci[it] * 8);
    };

    auto COMPUTE = [&](const u16* buf) {
        const u16* Ksb = buf;
        const u16* Vsb = buf + 16384;
        f32x16 st;
#pragma unroll
        for (int i = 0; i < 16; ++i) st[i] = 0.f;
        __builtin_amdgcn_s_setprio(1);
#pragma unroll
        for (int kk = 0; kk < 8; ++kk) {
            bf16x8 ak = *(const bf16x8*)(Ksb + kro + kk * 512);
            st = MFMA32(ak, aq[kk], st);
        }
        __builtin_amdgcn_s_setprio(0);
        float p[16];
#pragma unroll
        for (int i = 0; i < 16; ++i) p[i] = exp2f(st[i]);
        lloc += ((((p[0] + p[1]) + (p[2] + p[3])) + ((p[4] + p[5]) + (p[6] + p[7])))
               + (((p[8] + p[9]) + (p[10] + p[11])) + ((p[12] + p[13]) + (p[14] + p[15]))));
        bf16x8 pb[2];
#pragma unroll
        for (int ks = 0; ks < 2; ++ks) {
            u32 a0 = cvtpk(p[ks * 8 + 0], p[ks * 8 + 1]);
            u32 a1 = cvtpk(p[ks * 8 + 2], p[ks * 8 + 3]);
            u32 a2 = cvtpk(p[ks * 8 + 4], p[ks * 8 + 5]);
            u32 a3 = cvtpk(p[ks * 8 + 6], p[ks * 8 + 7]);
            auto s02 = __builtin_amdgcn_permlane32_swap(a0, a2, false, false);
            auto s13 = __builtin_amdgcn_permlane32_swap(a1, a3, false, false);
            union { u32 u[4]; bf16x8 v; } bb;
            bb.u[0] = s02[0]; bb.u[1] = s13[0]; bb.u[2] = s02[1]; bb.u[3] = s13[1];
            pb[ks] = bb.v;
        }
        __builtin_amdgcn_s_setprio(1);
#pragma unroll
        for (int cb = 0; cb < 4; ++cb) {
            bf16x8 av0 = *(const bf16x8*)(Vsb + vro + (cb * 2 + 0) * 512);
            bf16x8 av1 = *(const bf16x8*)(Vsb + vro + (cb * 2 + 1) * 512);
            o[cb] = MFMA32(av0, pb[0], o[cb]);
            o[cb] = MFMA32(av1, pb[1], o[cb]);
        }
        __builtin_amdgcn_s_setprio(0);
    };

    STAGE(B0, 0);
    __syncthreads();
    for (int t = 0; t < NT; t += 2) {
        if (t + 1 < NT) STAGE(B1, t + 1);
        COMPUTE(B0);
        __syncthreads();
        if (t + 2 < NT) STAGE(B0, t + 2);
        COMPUTE(B1);
        __syncthreads();
    }

    float lv = lloc + __shfl_xor(lloc, 32);

    float* const Om = (float*)smem;
    float* const Lm = (float*)(smem + 4 * 64 * OM_STRIDE * 4);

    const int qrow_w = qg * 32 + l31;
    const int crow0 = 4 * hi;
    {
        float* dst = Om + (size_t)(kg * 64 + qrow_w) * OM_STRIDE;
#pragma unroll
        for (int cb = 0; cb < 4; ++cb)
#pragma unroll
            for (int i = 0; i < 16; ++i) {
                int ch = cb * 32 + (i & 3) + 8 * (i >> 2) + crow0;
                dst[ch] = o[cb][i];
            }
        if (hi == 0) Lm[kg * 64 + qrow_w] = lv;
    }
    __syncthreads();

    const int qrow = tid >> 3;
    const int ch0 = (tid & 7) * 16;
    const float lsum = Lm[qrow] + Lm[64 + qrow] + Lm[128 + qrow] + Lm[192 + qrow];
    const float linv = 1.0f / lsum;
    float* op = out + ((size_t)b * N + q0 + qrow) * Fc + ch0;
#pragma unroll
    for (int j4 = 0; j4 < 4; ++j4) {
        f32x4 v;
#pragma unroll
        for (int jj = 0; jj < 4; ++jj) {
            int ch = ch0 + j4 * 4 + jj;
            float s = Om[(size_t)(0 * 64 + qrow) * OM_STRIDE + ch]
                    + Om[(size_t)(1 * 64 + qrow) * OM_STRIDE + ch]
                    + Om[(size_t)(2 * 64 + qrow) * OM_STRIDE + ch]
                    + Om[(size_t)(3 * 64 + qrow) * OM_STRIDE + ch];
            v[jj] = s * linv;
        }
        *(f32x4*)(op + j4 * 4) = v;
    }
}

extern "C" void kernel_launch(void* const* d_in, const int* in_sizes, int n_in,
                              void* d_out, int out_size, void* d_ws, size_t ws_size,
                              hipStream_t stream) {
    (void)in_sizes; (void)n_in; (void)out_size; (void)ws_size;
    const float* q_in  = (const float*)d_in[0];
    const float* kv_in = (const float*)d_in[1];
    const float* Wq = (const float*)d_in[2];
    const float* bq = (const float*)d_in[3];
    const float* Wk = (const float*)d_in[4];
    const float* bk = (const float*)d_in[5];
    const float* Wv = (const float*)d_in[6];
    const float* bv = (const float*)d_in[7];

    const size_t qkv = (size_t)BATCH * N * Fc;           // u16 elements
    u16* Kw  = (u16*)d_ws;                               // frag-major K (4 MB)
    u16* Vtw = Kw + qkv;                                 // frag-major V^T (4 MB)
    int* bar = (int*)((char*)d_ws + 2 * qkv * sizeof(u16));

    hipMemsetAsync(bar, 0, 128, stream);                 // reset grid barrier
    fused_kernel<<<dim3(64, BATCH), dim3(512), 0, stream>>>(
        q_in, kv_in, Wq, bq, Wk, bk, Wv, bv, Kw, Vtw, bar, (float*)d_out);
}